// Round 2
// baseline (58.373 us; speedup 1.0000x reference)
//
#include <hip/hip_runtime.h>

#define EPSV   1e-6f
#define SMOOTH 0.025f

__device__ __forceinline__ float fast_log2(float v) { return __builtin_amdgcn_logf(v); }
__device__ __forceinline__ float fast_exp2(float v) { return __builtin_amdgcn_exp2f(v); }

// PCEN pointwise: y = (x/(eps+M)^alpha + delta)^r - delta^r
__device__ __forceinline__ float pcen_elem(float xr, float M, float alpha,
                                           float delta, float r, float dr) {
    float m    = EPSV + M;
    float norm = xr * fast_exp2(-alpha * fast_log2(m));   // x * m^-alpha (avoids div)
    return fast_exp2(r * fast_log2(norm + delta)) - dr;
}

// One wave (64 lanes) per (b,c) row. Wave-parallel scan of the linear
// recurrence M_t = a*M_{t-1} + s*x_t via per-lane 4-elem local scan +
// 6-step Kogge-Stone cross-lane combine with decay powers a^(4*2^s).
__global__ __launch_bounds__(256) void pcen_ema_kernel(
    const float* __restrict__ x,
    const float* __restrict__ alpha_p,
    const float* __restrict__ delta_p,
    const float* __restrict__ r_p,
    float* __restrict__ y,
    int rows, int T)
{
    const int gid  = blockIdx.x * blockDim.x + threadIdx.x;
    const int row  = gid >> 6;
    const int lane = gid & 63;
    if (row >= rows) return;

    const float alpha = alpha_p[0];
    const float delta = delta_p[0];
    const float r     = r_p[0];
    const float dr    = fast_exp2(r * fast_log2(delta));

    const float a  = 1.0f - SMOOTH;   // 0.975
    const float b  = SMOOTH;
    const float a2 = a  * a;
    const float a3 = a2 * a;
    const float a4 = a2 * a2;
    // Kogge-Stone decay constants for 4-elem blocks: a^(4*2^s)
    const float c0 = a4;        // a^4
    const float c1 = c0 * c0;   // a^8
    const float c2 = c1 * c1;   // a^16
    const float c3 = c2 * c2;   // a^32
    const float c4 = c3 * c3;   // a^64
    const float c5 = c4 * c4;   // a^128

    // a^(4*lane) via binary powering (6 muls, once)
    float a4lane = 1.0f;
    if (lane & 1)  a4lane *= c0;
    if (lane & 2)  a4lane *= c1;
    if (lane & 4)  a4lane *= c2;
    if (lane & 8)  a4lane *= c3;
    if (lane & 16) a4lane *= c4;
    if (lane & 32) a4lane *= c5;
    // a^lane (for the 1-elem-per-lane tail)
    float alane = 1.0f;
    if (lane & 1)  alane *= a;
    if (lane & 2)  alane *= a2;
    if (lane & 4)  alane *= a4;
    if (lane & 8)  alane *= c1;   // a^8
    if (lane & 16) alane *= c2;   // a^16
    if (lane & 32) alane *= c3;   // a^32

    const long long base = (long long)row * T;
    const float4* __restrict__ xin  = (const float4*)(x + base);
    float4* __restrict__       yout = (float4*)(y + base);

    float m0 = 0.0f;                 // EMA carry entering each tile
    const int ntiles = T >> 8;       // 31 tiles of 256 for T=8000

    for (int tile = 0; tile < ntiles; ++tile) {
        float4 xv = xin[tile * 64 + lane];   // coalesced 16B/lane
        float x1 = fmaxf(xv.x, 0.0f), x2 = fmaxf(xv.y, 0.0f);
        float x3 = fmaxf(xv.z, 0.0f), x4 = fmaxf(xv.w, 0.0f);

        // local 4-elem scan with zero init: q_k = a*q_{k-1} + b*x_k
        float q1 = b * x1;
        float q2 = fmaf(a, q1, b * x2);
        float q3 = fmaf(a, q2, b * x3);
        float q4 = fmaf(a, q3, b * x4);

        // inclusive cross-lane scan of block sums with decay a^4
        float P = q4, up;
        up = __shfl_up(P, 1, 64);  P = fmaf(lane >= 1  ? c0 : 0.0f, up, P);
        up = __shfl_up(P, 2, 64);  P = fmaf(lane >= 2  ? c1 : 0.0f, up, P);
        up = __shfl_up(P, 4, 64);  P = fmaf(lane >= 4  ? c2 : 0.0f, up, P);
        up = __shfl_up(P, 8, 64);  P = fmaf(lane >= 8  ? c3 : 0.0f, up, P);
        up = __shfl_up(P, 16, 64); P = fmaf(lane >= 16 ? c4 : 0.0f, up, P);
        up = __shfl_up(P, 32, 64); P = fmaf(lane >= 32 ? c5 : 0.0f, up, P);
        float Pexc = __shfl_up(P, 1, 64);
        if (lane == 0) Pexc = 0.0f;

        // state entering this lane's 4-elem block
        float state = fmaf(a4lane, m0, Pexc);
        float M1 = fmaf(a,  state, q1);
        float M2 = fmaf(a2, state, q2);
        float M3 = fmaf(a3, state, q3);
        float M4 = fmaf(a4, state, q4);
        m0 = __shfl(M4, 63, 64);     // carry to next tile

        float4 yv;
        yv.x = pcen_elem(x1, M1, alpha, delta, r, dr);
        yv.y = pcen_elem(x2, M2, alpha, delta, r, dr);
        yv.z = pcen_elem(x3, M3, alpha, delta, r, dr);
        yv.w = pcen_elem(x4, M4, alpha, delta, r, dr);
        yout[tile * 64 + lane] = yv;
    }

    // tail: T - ntiles*256 elements (64 for T=8000), one per lane
    const int t0  = ntiles << 8;
    const int rem = T - t0;
    if (rem > 0) {
        const bool act = lane < rem;
        float xr = act ? fmaxf(x[base + t0 + lane], 0.0f) : 0.0f;
        float q = b * xr;
        float P = q, up;
        up = __shfl_up(P, 1, 64);  P = fmaf(lane >= 1  ? a  : 0.0f, up, P);
        up = __shfl_up(P, 2, 64);  P = fmaf(lane >= 2  ? a2 : 0.0f, up, P);
        up = __shfl_up(P, 4, 64);  P = fmaf(lane >= 4  ? a4 : 0.0f, up, P);
        up = __shfl_up(P, 8, 64);  P = fmaf(lane >= 8  ? c1 : 0.0f, up, P);
        up = __shfl_up(P, 16, 64); P = fmaf(lane >= 16 ? c2 : 0.0f, up, P);
        up = __shfl_up(P, 32, 64); P = fmaf(lane >= 32 ? c3 : 0.0f, up, P);
        float Pexc = __shfl_up(P, 1, 64);
        if (lane == 0) Pexc = 0.0f;
        float state = fmaf(alane, m0, Pexc);
        float M = fmaf(a, state, q);
        if (act) y[base + t0 + lane] = pcen_elem(xr, M, alpha, delta, r, dr);
    }
}

extern "C" void kernel_launch(void* const* d_in, const int* in_sizes, int n_in,
                              void* d_out, int out_size, void* d_ws, size_t ws_size,
                              hipStream_t stream) {
    const float* x     = (const float*)d_in[0];
    const float* alpha = (const float*)d_in[1];
    const float* delta = (const float*)d_in[2];
    const float* r     = (const float*)d_in[3];
    float* y = (float*)d_out;

    const int T     = 8000;
    const int total = in_sizes[0];
    const int rows  = total / T;          // 4096

    const int threads = rows * 64;        // one wave per row
    const int block   = 256;
    const int grid    = (threads + block - 1) / block;
    pcen_ema_kernel<<<grid, block, 0, stream>>>(x, alpha, delta, r, y, rows, T);
}